// Round 2
// baseline (218.500 us; speedup 1.0000x reference)
//
#include <hip/hip_runtime.h>
#include <stdint.h>

#define LTOT 20000
#define LPAD 20224   // 158*128 = 79*256
#define DV   4096
#define DH   1024
#define DE   100
#define NB   256

using f32x4 = __attribute__((ext_vector_type(4))) float;
using s16x8 = __attribute__((ext_vector_type(8))) short;
using f16x2 = __attribute__((ext_vector_type(2))) _Float16;

static __device__ __forceinline__ short f2bf(float x){
  union{float f; uint32_t u;} v; v.f = x;
  uint32_t r = (v.u + 0x7fffu + ((v.u >> 16) & 1u)) >> 16;
  return (short)r;
}

static __device__ __forceinline__ float dot2acc(f16x2 a, float c){
#if __has_builtin(__builtin_amdgcn_fdot2)
  return __builtin_amdgcn_fdot2(a, a, c, false);
#else
  float x = (float)a[0], y = (float)a[1];
  return __builtin_fmaf(x, x, __builtin_fmaf(y, y, c));
#endif
}

// ---------------------------------------------------------------------------
// Kernel 1: transpose label_vecs [20000][100] f32 -> lvT [50][LPAD] half2
// ---------------------------------------------------------------------------
__global__ __launch_bounds__(256) void prep_labels(const float* __restrict__ lab,
                                                   uint32_t* __restrict__ lvT){
  __shared__ float T[128 * 101];   // stride 101: gcd(101,32)=1, conflict-free
  int t = threadIdx.x;
  int lbase = blockIdx.x * 128;
  for (int i = t; i < 128 * 100; i += 256){
    int lloc = i / 100;
    int d = i - lloc * 100;
    int l = lbase + lloc;
    float v = (l < LTOT) ? lab[(size_t)l * DE + d] : 0.f;
    T[lloc * 101 + d] = v;
  }
  __syncthreads();
  int lloc = t & 127;
  int half = t >> 7;
  uint32_t lg = (uint32_t)(lbase + lloc);
  #pragma unroll
  for (int q = 0; q < 25; ++q){
    int d2 = half * 25 + q;
    f16x2 p;
    p[0] = (_Float16)T[lloc * 101 + 2 * d2];
    p[1] = (_Float16)T[lloc * 101 + 2 * d2 + 1];
    lvT[(size_t)d2 * LPAD + lg] = __builtin_bit_cast(uint32_t, p);
  }
}

// ---------------------------------------------------------------------------
// Kernel 2: H += relu(vfs) @ W1   (bf16 MFMA, 64x64 tiles, split-K=4, atomics)
// grid = 4(mt) * 16(nt) * 4(kt) = 256 blocks, 256 threads
// ---------------------------------------------------------------------------
__global__ __launch_bounds__(256) void gemm1(const float* __restrict__ A,
                                             const float* __restrict__ B,
                                             float* __restrict__ H){
  __shared__ __align__(16) short Als[64 * 40];  // [m][k], row pad 40 bf16
  __shared__ __align__(16) short Bls[64 * 40];  // [n][k], row pad 40 bf16
  int t = threadIdx.x;
  int bx = blockIdx.x;
  int kt = bx & 3, nt = (bx >> 2) & 15, mt = bx >> 6;
  int lane = t & 63, wv = t >> 6;
  int wm = wv >> 1, wn = wv & 1;
  int col = lane & 15, quad = lane >> 4;

  f32x4 acc00 = {}, acc01 = {}, acc10 = {}, acc11 = {};

  int ar = t >> 2, ac8 = (t & 3) * 8;       // A: 64 rows x 32 k, 8 floats/thread
  int bk = t >> 3, bn8 = (t & 7) * 8;       // B: 32 k x 64 n, 8 floats/thread

  const float* aBase = A + (size_t)(mt * 64 + ar) * DV + kt * 1024 + ac8;
  const float* bBase = B + (size_t)(kt * 1024 + bk) * DH + nt * 64 + bn8;

  for (int it = 0; it < 32; ++it){
    const float* ap = aBase + it * 32;
    f32x4 a0 = *(const f32x4*)ap;
    f32x4 a1 = *(const f32x4*)(ap + 4);
    const float* bp = bBase + (size_t)it * 32 * DH;
    f32x4 b0 = *(const f32x4*)bp;
    f32x4 b1 = *(const f32x4*)(bp + 4);

    s16x8 av;
    #pragma unroll
    for (int i = 0; i < 4; ++i){
      av[i]     = f2bf(__builtin_fmaxf(a0[i], 0.f));
      av[4 + i] = f2bf(__builtin_fmaxf(a1[i], 0.f));
    }
    short bs[8];
    #pragma unroll
    for (int i = 0; i < 4; ++i){ bs[i] = f2bf(b0[i]); bs[4 + i] = f2bf(b1[i]); }

    __syncthreads();   // previous iteration's frag reads done
    *(s16x8*)&Als[ar * 40 + ac8] = av;
    #pragma unroll
    for (int i = 0; i < 8; ++i) Bls[(bn8 + i) * 40 + bk] = bs[i];
    __syncthreads();

    s16x8 af0 = *(const s16x8*)&Als[(wm * 32 + col) * 40 + quad * 8];
    s16x8 af1 = *(const s16x8*)&Als[(wm * 32 + 16 + col) * 40 + quad * 8];
    s16x8 bf0 = *(const s16x8*)&Bls[(wn * 32 + col) * 40 + quad * 8];
    s16x8 bf1 = *(const s16x8*)&Bls[(wn * 32 + 16 + col) * 40 + quad * 8];

    acc00 = __builtin_amdgcn_mfma_f32_16x16x32_bf16(af0, bf0, acc00, 0, 0, 0);
    acc01 = __builtin_amdgcn_mfma_f32_16x16x32_bf16(af0, bf1, acc01, 0, 0, 0);
    acc10 = __builtin_amdgcn_mfma_f32_16x16x32_bf16(af1, bf0, acc10, 0, 0, 0);
    acc11 = __builtin_amdgcn_mfma_f32_16x16x32_bf16(af1, bf1, acc11, 0, 0, 0);
  }

  int rbase = mt * 64 + wm * 32 + quad * 4;
  int cbase = nt * 64 + wn * 32 + col;
  #pragma unroll
  for (int r = 0; r < 4; ++r){
    atomicAdd(&H[(size_t)(rbase + r) * DH + cbase],           acc00[r]);
    atomicAdd(&H[(size_t)(rbase + r) * DH + cbase + 16],      acc01[r]);
    atomicAdd(&H[(size_t)(rbase + 16 + r) * DH + cbase],      acc10[r]);
    atomicAdd(&H[(size_t)(rbase + 16 + r) * DH + cbase + 16], acc11[r]);
  }
}

// ---------------------------------------------------------------------------
// Kernel 3: E2 = pack_f16( relu(H + b1) @ W2 + b2 )   [256][50] half2
// grid = 4(mt) * 2(nt) = 8 blocks, 256 threads
// ---------------------------------------------------------------------------
__global__ __launch_bounds__(256) void gemm2(const float* __restrict__ H,
                                             const float* __restrict__ b1,
                                             const float* __restrict__ W2,
                                             const float* __restrict__ b2,
                                             uint32_t* __restrict__ E2){
  __shared__ __align__(16) short Als[64 * 40];
  __shared__ __align__(16) short Bls[64 * 40];
  __shared__ float Cls[64 * 66];
  int t = threadIdx.x;
  int mt = blockIdx.x >> 1, nt = blockIdx.x & 1;
  int lane = t & 63, wv = t >> 6;
  int wm = wv >> 1, wn = wv & 1;
  int col = lane & 15, quad = lane >> 4;

  f32x4 acc00 = {}, acc01 = {}, acc10 = {}, acc11 = {};
  int ar = t >> 2, ac8 = (t & 3) * 8;
  int bk = t >> 3, bn8 = (t & 7) * 8;

  for (int it = 0; it < 32; ++it){
    int k0 = it * 32;
    const float* ap = H + (size_t)(mt * 64 + ar) * DH + k0 + ac8;
    f32x4 a0 = *(const f32x4*)ap;
    f32x4 a1 = *(const f32x4*)(ap + 4);
    f32x4 c0 = *(const f32x4*)(b1 + k0 + ac8);
    f32x4 c1 = *(const f32x4*)(b1 + k0 + ac8 + 4);
    s16x8 av;
    #pragma unroll
    for (int i = 0; i < 4; ++i){
      av[i]     = f2bf(__builtin_fmaxf(a0[i] + c0[i], 0.f));
      av[4 + i] = f2bf(__builtin_fmaxf(a1[i] + c1[i], 0.f));
    }
    short bs[8];
    #pragma unroll
    for (int i = 0; i < 8; ++i){
      int n = nt * 64 + bn8 + i;
      bs[i] = (n < DE) ? f2bf(W2[(size_t)(k0 + bk) * DE + n]) : (short)0;
    }

    __syncthreads();
    *(s16x8*)&Als[ar * 40 + ac8] = av;
    #pragma unroll
    for (int i = 0; i < 8; ++i) Bls[(bn8 + i) * 40 + bk] = bs[i];
    __syncthreads();

    s16x8 af0 = *(const s16x8*)&Als[(wm * 32 + col) * 40 + quad * 8];
    s16x8 af1 = *(const s16x8*)&Als[(wm * 32 + 16 + col) * 40 + quad * 8];
    s16x8 bf0 = *(const s16x8*)&Bls[(wn * 32 + col) * 40 + quad * 8];
    s16x8 bf1 = *(const s16x8*)&Bls[(wn * 32 + 16 + col) * 40 + quad * 8];

    acc00 = __builtin_amdgcn_mfma_f32_16x16x32_bf16(af0, bf0, acc00, 0, 0, 0);
    acc01 = __builtin_amdgcn_mfma_f32_16x16x32_bf16(af0, bf1, acc01, 0, 0, 0);
    acc10 = __builtin_amdgcn_mfma_f32_16x16x32_bf16(af1, bf0, acc10, 0, 0, 0);
    acc11 = __builtin_amdgcn_mfma_f32_16x16x32_bf16(af1, bf1, acc11, 0, 0, 0);
  }

  // C -> LDS -> f16x2 pack
  int rb = wm * 32 + quad * 4;
  int cb = wn * 32 + col;
  #pragma unroll
  for (int r = 0; r < 4; ++r){
    Cls[(rb + r) * 66 + cb]           = acc00[r];
    Cls[(rb + r) * 66 + cb + 16]      = acc01[r];
    Cls[(rb + 16 + r) * 66 + cb]      = acc10[r];
    Cls[(rb + 16 + r) * 66 + cb + 16] = acc11[r];
  }
  __syncthreads();

  int mrow = t >> 2, c2b = (t & 3) * 8;
  #pragma unroll
  for (int cc = 0; cc < 8; ++cc){
    int c2 = c2b + cc;
    int d2 = nt * 32 + c2;
    if (d2 < 50){
      float x0 = Cls[mrow * 66 + 2 * c2]     + b2[2 * d2];
      float x1 = Cls[mrow * 66 + 2 * c2 + 1] + b2[2 * d2 + 1];
      E2[(size_t)(mt * 64 + mrow) * 50 + d2] =
          __builtin_bit_cast(uint32_t, __builtin_amdgcn_cvt_pkrtz(x0, x1));
    }
  }
}

// ---------------------------------------------------------------------------
// Kernel 4: scores[n][l] = -sqrt( sum_d relu(lv[l][d] - e[n][d])^2 )
// grid = (79 l-tiles, 16 n-tiles), 256 threads; thread = one l, loops 16 n
// ---------------------------------------------------------------------------
__global__ __launch_bounds__(256) void scores_k(const uint32_t* __restrict__ lvT,
                                                const uint32_t* __restrict__ E2,
                                                float* __restrict__ out){
  int t = threadIdx.x;
  int l = blockIdx.x * 256 + t;
  int n0 = blockIdx.y * 16;
  bool lok = l < LTOT;

  f16x2 lv[50];
  #pragma unroll
  for (int d2 = 0; d2 < 50; ++d2)
    lv[d2] = __builtin_bit_cast(f16x2, lvT[(size_t)d2 * LPAD + l]);

  f16x2 z = {(_Float16)0, (_Float16)0};
  float* op = out + (size_t)n0 * LTOT + l;
  for (int i = 0; i < 16; ++i){
    const uint32_t* er = E2 + (size_t)(n0 + i) * 50;   // block-uniform -> s_load
    float acc = 0.f;
    #pragma unroll
    for (int d2 = 0; d2 < 50; ++d2){
      f16x2 ev = __builtin_bit_cast(f16x2, er[d2]);
      f16x2 df = lv[d2] - ev;                          // v_pk_add_f16 (neg)
      df = __builtin_elementwise_max(df, z);           // v_pk_max_f16
      acc = dot2acc(df, acc);                          // v_dot2_f32_f16
    }
    if (lok) op[(size_t)i * LTOT] = -__builtin_sqrtf(acc);
  }
}

// ---------------------------------------------------------------------------
extern "C" void kernel_launch(void* const* d_in, const int* in_sizes, int n_in,
                              void* d_out, int out_size, void* d_ws, size_t ws_size,
                              hipStream_t stream){
  const float* vfs = (const float*)d_in[0];
  const float* lab = (const float*)d_in[1];
  const float* W1  = (const float*)d_in[2];
  const float* b1  = (const float*)d_in[3];
  const float* W2  = (const float*)d_in[4];
  const float* b2  = (const float*)d_in[5];
  float* out = (float*)d_out;

  char* ws = (char*)d_ws;
  uint32_t* lvT = (uint32_t*)ws;                               // 50*20224*4 = 4,044,800 B
  float*    H   = (float*)(ws + 4044800);                      // 256*1024*4 = 1,048,576 B
  uint32_t* E2  = (uint32_t*)(ws + 4044800 + 1048576);         // 256*50*4   =    51,200 B

  (void)hipMemsetAsync(H, 0, (size_t)NB * DH * sizeof(float), stream);
  prep_labels<<<158, 256, 0, stream>>>(lab, lvT);
  gemm1<<<256, 256, 0, stream>>>(vfs, W1, H);
  gemm2<<<8, 256, 0, stream>>>(H, b1, W2, b2, E2);
  scores_k<<<dim3(79, 16), 256, 0, stream>>>(lvT, E2, out);
}

// Round 3
// 170.625 us; speedup vs baseline: 1.2806x; 1.2806x over previous
//
#include <hip/hip_runtime.h>
#include <stdint.h>

#define LTOT 20000
#define LPAD 20224   // 158*128 = 79*256
#define DV   4096
#define DH   1024
#define DE   100
#define NB   256

using f32x4 = __attribute__((ext_vector_type(4))) float;
using s16x8 = __attribute__((ext_vector_type(8))) short;
using f16x2 = __attribute__((ext_vector_type(2))) _Float16;

static __device__ __forceinline__ short f2bf(float x){
  union{float f; uint32_t u;} v; v.f = x;
  uint32_t r = (v.u + 0x7fffu + ((v.u >> 16) & 1u)) >> 16;
  return (short)r;
}

static __device__ __forceinline__ float dot2acc(f16x2 a, float c){
#if __has_builtin(__builtin_amdgcn_fdot2)
  return __builtin_amdgcn_fdot2(a, a, c, false);
#else
  float x = (float)a[0], y = (float)a[1];
  return __builtin_fmaf(x, x, __builtin_fmaf(y, y, c));
#endif
}

// ---------------------------------------------------------------------------
// Kernel 1: blocks 0..157: transpose label_vecs [20000][100] f32 -> lvT [50][LPAD] half2
//           blocks 158..165: transpose W2 [1024][100] -> W2T [100][1024] f32
// ---------------------------------------------------------------------------
__global__ __launch_bounds__(256) void prep_labels(const float* __restrict__ lab,
                                                   uint32_t* __restrict__ lvT,
                                                   const float* __restrict__ W2,
                                                   float* __restrict__ W2T){
  __shared__ float T[128 * 101];   // stride 101: gcd(101,32)=1, conflict-free
  int t = threadIdx.x;
  int bx = blockIdx.x;
  if (bx < 158){
    int lbase = bx * 128;
    for (int i = t; i < 128 * 100; i += 256){
      int lloc = i / 100;
      int d = i - lloc * 100;
      int l = lbase + lloc;
      float v = (l < LTOT) ? lab[(size_t)l * DE + d] : 0.f;
      T[lloc * 101 + d] = v;
    }
    __syncthreads();
    int lloc = t & 127;
    int half = t >> 7;
    uint32_t lg = (uint32_t)(lbase + lloc);
    #pragma unroll
    for (int q = 0; q < 25; ++q){
      int d2 = half * 25 + q;
      f16x2 p;
      p[0] = (_Float16)T[lloc * 101 + 2 * d2];
      p[1] = (_Float16)T[lloc * 101 + 2 * d2 + 1];
      lvT[(size_t)d2 * LPAD + lg] = __builtin_bit_cast(uint32_t, p);
    }
  } else {
    int k0 = (bx - 158) * 128;
    for (int i = t; i < 128 * 100; i += 256){
      int kk = i / 100;
      int d = i - kk * 100;
      T[kk * 101 + d] = W2[(size_t)(k0 + kk) * DE + d];
    }
    __syncthreads();
    for (int i = t; i < 100 * 128; i += 256){
      int d = i >> 7, kk = i & 127;
      W2T[(size_t)d * DH + k0 + kk] = T[kk * 101 + d];
    }
  }
}

// ---------------------------------------------------------------------------
// Kernel 2: H += relu(vfs) @ W1   (bf16 MFMA, 64x64 tiles, split-K=16, atomics)
// grid = 4(mt) * 16(nt) * 16(kt) = 1024 blocks (4/CU -> latency hiding), 256 thr
// ---------------------------------------------------------------------------
__global__ __launch_bounds__(256) void gemm1(const float* __restrict__ A,
                                             const float* __restrict__ B,
                                             float* __restrict__ H){
  __shared__ __align__(16) short Als[64 * 40];  // [m][k], row pad 40 bf16
  __shared__ __align__(16) short Bls[64 * 40];  // [n][k], row pad 40 bf16
  int t = threadIdx.x;
  int bx = blockIdx.x;
  int kt = bx & 15, nt = (bx >> 4) & 15, mt = bx >> 8;
  int lane = t & 63, wv = t >> 6;
  int wm = wv >> 1, wn = wv & 1;
  int col = lane & 15, quad = lane >> 4;

  f32x4 acc00 = {}, acc01 = {}, acc10 = {}, acc11 = {};

  int ar = t >> 2, ac8 = (t & 3) * 8;       // A: 64 rows x 32 k, 8 floats/thread
  int bk = t >> 3, bn8 = (t & 7) * 8;       // B: 32 k x 64 n, 8 floats/thread

  const float* aBase = A + (size_t)(mt * 64 + ar) * DV + kt * 256 + ac8;
  const float* bBase = B + (size_t)(kt * 256 + bk) * DH + nt * 64 + bn8;

  for (int it = 0; it < 8; ++it){
    const float* ap = aBase + it * 32;
    f32x4 a0 = *(const f32x4*)ap;
    f32x4 a1 = *(const f32x4*)(ap + 4);
    const float* bp = bBase + (size_t)it * 32 * DH;
    f32x4 b0 = *(const f32x4*)bp;
    f32x4 b1 = *(const f32x4*)(bp + 4);

    s16x8 av;
    #pragma unroll
    for (int i = 0; i < 4; ++i){
      av[i]     = f2bf(__builtin_fmaxf(a0[i], 0.f));
      av[4 + i] = f2bf(__builtin_fmaxf(a1[i], 0.f));
    }
    short bs[8];
    #pragma unroll
    for (int i = 0; i < 4; ++i){ bs[i] = f2bf(b0[i]); bs[4 + i] = f2bf(b1[i]); }

    __syncthreads();   // previous iteration's frag reads done
    *(s16x8*)&Als[ar * 40 + ac8] = av;
    #pragma unroll
    for (int i = 0; i < 8; ++i) Bls[(bn8 + i) * 40 + bk] = bs[i];
    __syncthreads();

    s16x8 af0 = *(const s16x8*)&Als[(wm * 32 + col) * 40 + quad * 8];
    s16x8 af1 = *(const s16x8*)&Als[(wm * 32 + 16 + col) * 40 + quad * 8];
    s16x8 bf0 = *(const s16x8*)&Bls[(wn * 32 + col) * 40 + quad * 8];
    s16x8 bf1 = *(const s16x8*)&Bls[(wn * 32 + 16 + col) * 40 + quad * 8];

    acc00 = __builtin_amdgcn_mfma_f32_16x16x32_bf16(af0, bf0, acc00, 0, 0, 0);
    acc01 = __builtin_amdgcn_mfma_f32_16x16x32_bf16(af0, bf1, acc01, 0, 0, 0);
    acc10 = __builtin_amdgcn_mfma_f32_16x16x32_bf16(af1, bf0, acc10, 0, 0, 0);
    acc11 = __builtin_amdgcn_mfma_f32_16x16x32_bf16(af1, bf1, acc11, 0, 0, 0);
  }

  int rbase = mt * 64 + wm * 32 + quad * 4;
  int cbase = nt * 64 + wn * 32 + col;
  #pragma unroll
  for (int r = 0; r < 4; ++r){
    atomicAdd(&H[(size_t)(rbase + r) * DH + cbase],           acc00[r]);
    atomicAdd(&H[(size_t)(rbase + r) * DH + cbase + 16],      acc01[r]);
    atomicAdd(&H[(size_t)(rbase + 16 + r) * DH + cbase],      acc10[r]);
    atomicAdd(&H[(size_t)(rbase + 16 + r) * DH + cbase + 16], acc11[r]);
  }
}

// ---------------------------------------------------------------------------
// Kernel 3: E2 = pack_f16( relu(H + b1) @ W2 + b2 )  [256][50] half2
// matvec style: 256 blocks (1 per row), 256 thr: thread = (d-pair, K-slice)
// W2T is L2-resident (400 KB); hs reads are wave-uniform broadcasts.
// ---------------------------------------------------------------------------
__global__ __launch_bounds__(256) void gemm2(const float* __restrict__ H,
                                             const float* __restrict__ b1,
                                             const float* __restrict__ W2T,
                                             const float* __restrict__ b2,
                                             uint32_t* __restrict__ E2){
  __shared__ float hs[DH];
  __shared__ float red[4][64][2];
  int t = threadIdx.x;
  int n = blockIdx.x;

  f32x4 hv = *(const f32x4*)&H[(size_t)n * DH + t * 4];
  f32x4 bv = *(const f32x4*)&b1[t * 4];
  f32x4 hr;
  #pragma unroll
  for (int i = 0; i < 4; ++i) hr[i] = __builtin_fmaxf(hv[i] + bv[i], 0.f);
  *(f32x4*)&hs[t * 4] = hr;
  __syncthreads();

  int d2 = t & 63, ks = t >> 6;      // wave = one ks slice -> uniform hs reads
  float a00 = 0.f, a01 = 0.f, a10 = 0.f, a11 = 0.f;
  if (d2 < 50){
    const float* w0 = W2T + (size_t)(2 * d2) * DH + ks * 256;
    const float* w1 = w0 + DH;
    const float* hp = hs + ks * 256;
    #pragma unroll 4
    for (int kk = 0; kk < 256; kk += 8){
      f32x4 h0 = *(const f32x4*)(hp + kk);
      f32x4 h1 = *(const f32x4*)(hp + kk + 4);
      f32x4 wa = *(const f32x4*)(w0 + kk);
      f32x4 wb = *(const f32x4*)(w0 + kk + 4);
      f32x4 wc = *(const f32x4*)(w1 + kk);
      f32x4 wd = *(const f32x4*)(w1 + kk + 4);
      #pragma unroll
      for (int i = 0; i < 4; ++i){
        a00 = __builtin_fmaf(wa[i], h0[i], a00);
        a01 = __builtin_fmaf(wb[i], h1[i], a01);
        a10 = __builtin_fmaf(wc[i], h0[i], a10);
        a11 = __builtin_fmaf(wd[i], h1[i], a11);
      }
    }
  }
  red[ks][d2][0] = a00 + a01;
  red[ks][d2][1] = a10 + a11;
  __syncthreads();
  if (t < 50){
    float s0 = red[0][t][0] + red[1][t][0] + red[2][t][0] + red[3][t][0] + b2[2 * t];
    float s1 = red[0][t][1] + red[1][t][1] + red[2][t][1] + red[3][t][1] + b2[2 * t + 1];
    E2[(size_t)n * 50 + t] =
        __builtin_bit_cast(uint32_t, __builtin_amdgcn_cvt_pkrtz(s0, s1));
  }
}

// ---------------------------------------------------------------------------
// Kernel 4: scores[n][l] = -sqrt( sum_d relu(lv[l][d] - e[n][d])^2 )
// grid = (79 l-tiles, 16 n-tiles), 256 threads; thread = one l, loops 16 n
// ---------------------------------------------------------------------------
__global__ __launch_bounds__(256) void scores_k(const uint32_t* __restrict__ lvT,
                                                const uint32_t* __restrict__ E2,
                                                float* __restrict__ out){
  int t = threadIdx.x;
  int l = blockIdx.x * 256 + t;
  int n0 = blockIdx.y * 16;
  bool lok = l < LTOT;

  f16x2 lv[50];
  #pragma unroll
  for (int d2 = 0; d2 < 50; ++d2)
    lv[d2] = __builtin_bit_cast(f16x2, lvT[(size_t)d2 * LPAD + l]);

  f16x2 z = {(_Float16)0, (_Float16)0};
  float* op = out + (size_t)n0 * LTOT + l;
  for (int i = 0; i < 16; ++i){
    const uint32_t* er = E2 + (size_t)(n0 + i) * 50;
    float acc0 = 0.f, acc1 = 0.f;     // two chains: halve fdot2 dep latency
    #pragma unroll
    for (int d2 = 0; d2 < 50; d2 += 2){
      f16x2 ev0 = __builtin_bit_cast(f16x2, er[d2]);
      f16x2 ev1 = __builtin_bit_cast(f16x2, er[d2 + 1]);
      f16x2 df0 = lv[d2] - ev0;
      f16x2 df1 = lv[d2 + 1] - ev1;
      df0 = __builtin_elementwise_max(df0, z);
      df1 = __builtin_elementwise_max(df1, z);
      acc0 = dot2acc(df0, acc0);
      acc1 = dot2acc(df1, acc1);
    }
    if (lok) op[(size_t)i * LTOT] = -__builtin_sqrtf(acc0 + acc1);
  }
}

// ---------------------------------------------------------------------------
extern "C" void kernel_launch(void* const* d_in, const int* in_sizes, int n_in,
                              void* d_out, int out_size, void* d_ws, size_t ws_size,
                              hipStream_t stream){
  const float* vfs = (const float*)d_in[0];
  const float* lab = (const float*)d_in[1];
  const float* W1  = (const float*)d_in[2];
  const float* b1  = (const float*)d_in[3];
  const float* W2  = (const float*)d_in[4];
  const float* b2  = (const float*)d_in[5];
  float* out = (float*)d_out;

  char* ws = (char*)d_ws;
  uint32_t* lvT = (uint32_t*)ws;                               // 50*20224*4 = 4,044,800 B
  float*    H   = (float*)(ws + 4044800);                      // 256*1024*4 = 1,048,576 B
  uint32_t* E2  = (uint32_t*)(ws + 4044800 + 1048576);         // 256*50*4   =    51,200 B
  float*    W2T = (float*)(ws + 4044800 + 1048576 + 51200);    // 100*1024*4 =   409,600 B

  (void)hipMemsetAsync(H, 0, (size_t)NB * DH * sizeof(float), stream);
  prep_labels<<<166, 256, 0, stream>>>(lab, lvT, W2, W2T);
  gemm1<<<1024, 256, 0, stream>>>(vfs, W1, H);
  gemm2<<<256, 256, 0, stream>>>(H, b1, W2T, b2, E2);
  scores_k<<<dim3(79, 16), 256, 0, stream>>>(lvT, E2, out);
}